// Round 5
// baseline (418.534 us; speedup 1.0000x reference)
//
#include <hip/hip_runtime.h>
#include <stdint.h>

#define BB 16
#define NN 102000
#define NCLS 35
#define RSTRIDE 40
#define PRE 1024
#define CAP 2048
#define MAXDET 300
#define NBUCK 4096
#define CONF_T 0.25f
#define IOU_T 0.45f
#define BUCK_BASE 0x3E800000u
#define HI_BUCK 3584u        /* bucket of score 0.875; cut lands ~4014 on this data */
#define HI_BITS 0x3F600000u  /* float bits of 0.875 == BUCK_BASE + (HI_BUCK<<12) */
#define GL_CAP 16384         /* per-batch compact-list capacity (~10K expected) */
#define GCNT_STRIDE 64       /* uints between per-batch counters: 256 B apart */

// ---- workspace layout (bytes) ----
#define SCORES_OFF ((size_t)0)
#define SCORES_BYTES ((size_t)BB * NN * 4)                 // 6,528,000
#define GCNT_OFF (SCORES_OFF + SCORES_BYTES)
#define GCNT_BYTES ((size_t)BB * GCNT_STRIDE * 4)          // 4,096
#define BOXES_OFF (GCNT_OFF + GCNT_BYTES)
#define BOXES_BYTES ((size_t)BB * PRE * 16)
#define SVAL_OFF (BOXES_OFF + BOXES_BYTES)
#define SVAL_BYTES ((size_t)BB * PRE * 4)
#define CLS_OFF (SVAL_OFF + SVAL_BYTES)
#define CLS_BYTES ((size_t)BB * PRE * 4)
#define MASK_OFF (CLS_OFF + CLS_BYTES)
#define MASK_BYTES ((size_t)BB * PRE * 16 * 8)             // 2 MB
#define GLIST_OFF (MASK_OFF + MASK_BYTES)
#define GLIST_BYTES ((size_t)BB * GL_CAP * 8)              // 2 MB

// padded bitonic index: breaks mod-16 bank aliasing of u64 keys
__device__ __forceinline__ int KS(int i) { return i + (i >> 4); }
#define CAPP (CAP + (CAP >> 4))

// ============================================================
// Kernel 1 (cooperative): 8 lanes per row. One wave-instr reads 8 rows'
// 128B segments (~2.3 line-requests/row vs 9 for the per-thread version:
// TA/L1 request-bound theory). max-reduce via 3x shfl_xor; obj broadcast
// via shfl. NO global histogram (cut is derived in k_sort from the
// compact list). Per-wave queue count carried in a uniform REGISTER
// (an LDS count read-after-other-lane-write would be compiler-hoisted).
// One returning atomic per block on a 256B-padded counter (Round-1
// lesson: shared-line returning atomics serialized to 320us).
// ============================================================
__global__ __launch_bounds__(256) void k_score(const float* __restrict__ pred,
                                               float* __restrict__ scores,
                                               unsigned int* __restrict__ gcnt,
                                               unsigned long long* __restrict__ glist) {
    __shared__ unsigned long long wbuf[4 * 64];   // per-wave candidate queue
    __shared__ unsigned int wcnt[4], woff[4];
    __shared__ unsigned int sBase;
    int b = blockIdx.y, tid = threadIdx.x;
    int lane = tid & 63, w = tid >> 6;
    int sub = lane & 7, rg = lane >> 3;
    int rowBase = blockIdx.x * 256 + w * 8 + rg;
    unsigned int wtotal = 0u;                     // wave-uniform running count
#pragma unroll
    for (int p = 0; p < 8; ++p) {
        int row = rowBase + p * 32;
        bool rv = row < NN;
        const float4* rp = (const float4*)(pred + ((size_t)b * NN + row) * RSTRIDE);
        float4 va = make_float4(0.0f, 0.0f, 0.0f, 0.0f);
        float4 vb = make_float4(0.0f, 0.0f, 0.0f, 0.0f);
        if (rv) va = rp[1 + sub];                 // floats 4+4sub..7+4sub
        if (rv && sub == 0) vb = rp[9];           // floats 36..39 (cls31..34)
        float f0 = (sub == 0) ? va.y : va.x;      // sub0's va.x is obj: exclude
        float lm = fmaxf(fmaxf(f0, va.y), fmaxf(va.z, va.w));
        lm = fmaxf(lm, fmaxf(fmaxf(vb.x, vb.y), fmaxf(vb.z, vb.w)));
        lm = fmaxf(lm, __shfl_xor(lm, 1));
        lm = fmaxf(lm, __shfl_xor(lm, 2));
        lm = fmaxf(lm, __shfl_xor(lm, 4));        // 8-lane group max of cls
        float obj = __shfl(va.x, lane & ~7);      // group's sub0 holds obj
        float conf = lm * obj;   // == max_j fl(cls_j*obj): monotone rounding, obj>0
        float score = (obj > CONF_T && conf > CONF_T) ? conf : 0.0f;
        unsigned int bits = __float_as_uint(score);
        if (sub == 0 && rv) scores[(size_t)b * NN + row] = score;
        bool want = (sub == 0) && rv && (bits >= HI_BITS) && (score > 0.0f);
        unsigned long long m = __ballot(want);
        if (want) {
            unsigned int off = wtotal + (unsigned int)__popcll(m & ((1ull << lane) - 1ull));
            wbuf[w * 64 + off] = ((unsigned long long)bits << 32) |
                                 (unsigned int)(~(unsigned int)row);
        }
        wtotal += (unsigned int)__popcll(m);      // uniform across wave
    }
    if (lane == 0) wcnt[w] = wtotal;
    __syncthreads();
    if (tid == 0) {
        unsigned int acc = 0;
        for (int k = 0; k < 4; ++k) { woff[k] = acc; acc += wcnt[k]; }
        sBase = acc ? atomicAdd(&gcnt[b * GCNT_STRIDE], acc) : 0u;
    }
    __syncthreads();
    for (unsigned int i = (unsigned int)lane; i < wtotal; i += 64u) {
        unsigned int pos = sBase + woff[w] + i;
        if (pos < GL_CAP) glist[(size_t)b * GL_CAP + pos] = wbuf[w * 64 + i];
    }
}

// ============================================================
// Kernel 2 (fused cut+sort): cut derived from a 512-bucket LDS histogram
// of the compact list (no global ghist). Exact cold path: full 4096-bucket
// LDS histogram from scores[] + rescan (taken iff the list can't prove
// cut >= HI_BUCK, i.e. <1024 boxes score >= 0.875, or list overflow).
// Then bitonic sort desc of 2048 padded keys + top-1024 gather.
// key = (score_bits << 32) | ~idx  -> u64 desc == (value desc, idx asc)
// ============================================================
__global__ __launch_bounds__(1024) void k_sort(const float* __restrict__ scores,
                                               const unsigned int* __restrict__ gcnt,
                                               const unsigned long long* __restrict__ glist,
                                               const float* __restrict__ pred,
                                               float4* __restrict__ boxesWS,
                                               float* __restrict__ svalWS,
                                               float* __restrict__ clsWS) {
    __shared__ int sA[1024], sB[1024];                     // 8 KB
    __shared__ unsigned int hh[512];                       // 2 KB (hot-path hist)
    __shared__ unsigned int fh[NBUCK];                     // 16 KB (cold-path hist)
    __shared__ int cutSh;
    __shared__ unsigned long long keys[CAPP];              // 17.4 KB
    __shared__ unsigned int nloc;
    int b = blockIdx.x, tid = threadIdx.x;
    unsigned int gn = gcnt[b * GCNT_STRIDE];
    if (tid == 0) { cutSh = -1; nloc = 0u; }
    if (tid < 512) hh[tid] = 0u;
    for (int k = tid; k < CAP; k += 1024) keys[KS(k)] = 0ull;
    __syncthreads();
    const unsigned long long* gl = glist + (size_t)b * GL_CAP;
    bool fast = (gn <= (unsigned int)GL_CAP);
    if (fast) {
        for (unsigned int it = tid; it < gn; it += 1024u) {
            unsigned int bits = (unsigned int)(gl[it] >> 32);
            unsigned int bk = (bits - BUCK_BASE) >> 12;
            if (bk > NBUCK - 1u) bk = NBUCK - 1u;
            atomicAdd(&hh[bk - HI_BUCK], 1u);              // bk >= HI_BUCK by constr.
        }
        __syncthreads();
        if (tid < 512) sA[tid] = (int)hh[tid];
        __syncthreads();
        int* src = sA; int* dst = sB;
        for (int off = 1; off < 512; off <<= 1) {
            if (tid < 512) {
                int x = src[tid];
                if (tid + off < 512) x += src[tid + off];
                dst[tid] = x;
            }
            __syncthreads();
            int* t_ = src; src = dst; dst = t_;
        }
        if (tid < 512) {
            int suf = src[tid];
            int nx = (tid + 1 < 512) ? src[tid + 1] : 0;
            if (suf >= PRE && nx < PRE) cutSh = (int)HI_BUCK + tid;
        }
        __syncthreads();
    }
    int cut = cutSh;
    if (fast && cut >= (int)HI_BUCK) {
        // hot gather: compact list fully covers buckets >= cut
        for (unsigned int it = tid; it < gn; it += 1024u) {
            unsigned long long key = gl[it];
            unsigned int bits = (unsigned int)(key >> 32);
            unsigned int bk = (bits - BUCK_BASE) >> 12;
            if (bk > NBUCK - 1u) bk = NBUCK - 1u;
            if ((int)bk >= cut) {
                unsigned int pos = atomicAdd(&nloc, 1u);
                if (pos < CAP) keys[KS((int)pos)] = key;
            }
        }
    } else {
        // cold exact path (never taken on this data): full hist + rescan
        for (int k = tid; k < NBUCK; k += 1024) fh[k] = 0u;
        __syncthreads();
        const float* sb = scores + (size_t)b * NN;
        for (int it = tid; it < NN; it += 1024) {
            float s = sb[it];
            if (s > 0.0f) {
                unsigned int bits = __float_as_uint(s);
                unsigned int bk = (bits - BUCK_BASE) >> 12;
                if (bk > NBUCK - 1u) bk = NBUCK - 1u;
                atomicAdd(&fh[bk], 1u);
            }
        }
        __syncthreads();
        int h0 = fh[4 * tid + 0], h1 = fh[4 * tid + 1];
        int h2 = fh[4 * tid + 2], h3 = fh[4 * tid + 3];
        if (tid == 0) cutSh = 0;
        sA[tid] = h0 + h1 + h2 + h3;
        __syncthreads();
        int* src = sA; int* dst = sB;
        for (int off = 1; off < 1024; off <<= 1) {
            int x = src[tid];
            if (tid + off < 1024) x += src[tid + off];
            dst[tid] = x;
            __syncthreads();
            int* t_ = src; src = dst; dst = t_;
        }
        int nxt = (tid + 1 < 1024) ? src[tid + 1] : 0;
        int s3 = h3 + nxt;
        int s2 = h2 + s3;
        int s1 = h1 + s2;
        int s0 = h0 + s1;
        if (s0 >= PRE && s1 < PRE) cutSh = 4 * tid + 0;
        if (s1 >= PRE && s2 < PRE) cutSh = 4 * tid + 1;
        if (s2 >= PRE && s3 < PRE) cutSh = 4 * tid + 2;
        if (s3 >= PRE && nxt < PRE) cutSh = 4 * tid + 3;
        __syncthreads();
        unsigned int ccut = (unsigned int)cutSh;
        const float4* sb4 = (const float4*)sb;
        for (int it = tid; it < NN / 4; it += 1024) {
            float4 s4 = sb4[it];
            float sv[4] = {s4.x, s4.y, s4.z, s4.w};
#pragma unroll
            for (int u = 0; u < 4; ++u) {
                float s = sv[u];
                if (s > 0.0f) {
                    unsigned int bits = __float_as_uint(s);
                    unsigned int bk = (bits - BUCK_BASE) >> 12;
                    if (bk > NBUCK - 1u) bk = NBUCK - 1u;
                    if (bk >= ccut) {
                        unsigned int pos = atomicAdd(&nloc, 1u);
                        unsigned int idx = (unsigned int)(it * 4 + u);
                        if (pos < CAP)
                            keys[KS((int)pos)] = ((unsigned long long)bits << 32) |
                                                 (unsigned int)(~idx);
                    }
                }
            }
        }
    }
    __syncthreads();

    // ---- bitonic sort desc (padded indices -> no 8-way bank alias) ----
    for (int k = 2; k <= CAP; k <<= 1) {
        for (int j = k >> 1; j > 0; j >>= 1) {
            int p = ((tid & ~(j - 1)) << 1) | (tid & (j - 1));
            int q = p | j;
            int pp = KS(p), qq = KS(q);
            unsigned long long a = keys[pp], c = keys[qq];
            bool desc = (p & k) == 0;
            bool sw = desc ? (a < c) : (a > c);
            if (sw) { keys[pp] = c; keys[qq] = a; }
            __syncthreads();
        }
    }

    // ---- top-1024 gather + box/cls recompute ----
    unsigned long long key = keys[KS(tid)];
    unsigned int bits = (unsigned int)(key >> 32);
    unsigned int idx = ~(unsigned int)key;
    float sc = __uint_as_float(bits);
    if (bits == 0u || idx >= NN) { idx = 0; sc = 0.0f; }   // pad guard
    const float4* row = (const float4*)(pred + ((size_t)b * NN + idx) * RSTRIDE);
    float4 r0 = row[0];
    float4 r1 = row[1];
    float obj = r1.x;
    float best = r1.y * obj; int bj = 0;
    float p1 = r1.z * obj; if (p1 > best) { best = p1; bj = 1; }
    float p2 = r1.w * obj; if (p2 > best) { best = p2; bj = 2; }
#pragma unroll
    for (int kk = 2; kk <= 9; ++kk) {
        float4 r = row[kk];
        int base = (kk - 2) * 4 + 3;
        float q0 = r.x * obj; if (q0 > best) { best = q0; bj = base + 0; }
        float q1 = r.y * obj; if (q1 > best) { best = q1; bj = base + 1; }
        float q2 = r.z * obj; if (q2 > best) { best = q2; bj = base + 2; }
        float q3 = r.w * obj; if (q3 > best) { best = q3; bj = base + 3; }
    }
    float hx = r0.z * 0.5f;   // exact (power-of-two scale)
    float hy = r0.w * 0.5f;
    boxesWS[b * PRE + tid] = make_float4(r0.x - hx, r0.y - hy, r0.x + hx, r0.y + hy);
    svalWS[b * PRE + tid] = sc;
    clsWS[b * PRE + tid] = (float)bj;
}

// ============================================================
// Kernel 3: column-major suppression mask (wide: 256 blocks/batch --
// Round-3 lesson: this phase needs the 4096-block grid, NOT fusion).
// maskC[b][j][c] bit l  <=>  i=64c+l < j  &&  valid[i]  &&  IoU(i,j) > 0.45
// ============================================================
__global__ __launch_bounds__(256) void k_mask(const float4* __restrict__ boxesWS,
                                              const float* __restrict__ svalWS,
                                              unsigned long long* __restrict__ maskC) {
    __shared__ float bx1[PRE], by1[PRE], bx2[PRE], by2[PRE], bar[PRE], bsv[PRE];
    int b = blockIdx.y, tid = threadIdx.x;
    for (int i = tid; i < PRE; i += 256) {
        float4 bx = boxesWS[b * PRE + i];
        bx1[i] = bx.x; by1[i] = bx.y; bx2[i] = bx.z; by2[i] = bx.w;
        float aw = fmaxf(bx.z - bx.x, 0.0f);
        float ah = fmaxf(bx.w - bx.y, 0.0f);
        bar[i] = aw * ah;
        bsv[i] = svalWS[b * PRE + i];
    }
    __syncthreads();
    int j = blockIdx.x * 4 + (tid >> 6);
    int lane = tid & 63;
    float jx1 = bx1[j], jy1 = by1[j], jx2 = bx2[j], jy2 = by2[j], ja = bar[j];
    unsigned long long* out = maskC + ((size_t)b * PRE + j) * 16;
    for (int c = 0; c < 16; ++c) {
        unsigned long long word = 0ull;
        if (c * 64 < j) {                      // wave-uniform branch
            int i = c * 64 + lane;
            bool bit = false;
            if (i < j && bsv[i] > 0.0f) {
                float ltx = fmaxf(bx1[i], jx1), lty = fmaxf(by1[i], jy1);
                float rbx = fminf(bx2[i], jx2), rby = fminf(by2[i], jy2);
                float wx = fmaxf(rbx - ltx, 0.0f);
                float wy = fmaxf(rby - lty, 0.0f);
                float inter = wx * wy;                       // two uses -> no contraction
                float denom = ((bar[i] + ja) - inter) + 1e-7f;
                bit = (inter / denom) > IOU_T;               // IEEE divide, like reference
            }
            word = __ballot(bit);
        }
        if (lane == 0) out[c] = word;
    }
}

// ============================================================
// Kernel 4: fixpoint NMS (2 barriers/iter) + exact top-300 ordering.
// ============================================================
__global__ __launch_bounds__(1024) void k_nms_out(const float4* __restrict__ boxesWS,
                                                  const float* __restrict__ svalWS,
                                                  const float* __restrict__ clsWS,
                                                  const unsigned long long* __restrict__ maskC,
                                                  float* __restrict__ out) {
    __shared__ unsigned long long supp[16];
    __shared__ int lastch;
    __shared__ int wtot[16], woff[17];
    int b = blockIdx.x, tid = threadIdx.x;
    int lane = tid & 63, w = tid >> 6;
    unsigned long long cm[16];
    const unsigned long long* mrow = maskC + ((size_t)b * PRE + tid) * 16;
#pragma unroll
    for (int k = 0; k < 16; ++k) cm[k] = mrow[k];
    float sv = svalWS[b * PRE + tid];
    if (tid < 16) supp[tid] = 0ull;
    if (tid == 0) lastch = -1;
    __syncthreads();
    for (int it = 0; it < PRE + 2; ++it) {
        bool nb = false;
#pragma unroll
        for (int k = 0; k < 16; ++k) nb |= ((cm[k] & ~supp[k]) != 0ull);
        unsigned long long word = __ballot(nb);
        __syncthreads();                       // all waves done reading supp
        if (lane == 0) {
            if (word != supp[w]) lastch = it;  // benign same-value multi-writer
            supp[w] = word;
        }
        __syncthreads();                       // supp + lastch published
        if (lastch != it) break;
    }
    bool keep = (sv > 0.0f) && !((supp[w] >> lane) & 1ull);
    unsigned long long km = __ballot(keep);
    int lp = __popcll(km & ((lane == 0) ? 0ull : ((1ull << lane) - 1ull)));
    if (lane == 0) wtot[w] = __popcll(km);
    __syncthreads();
    if (tid == 0) {
        int acc = 0;
        for (int k = 0; k < 16; ++k) { woff[k] = acc; acc += wtot[k]; }
        woff[16] = acc;
    }
    __syncthreads();
    int K = woff[16];
    int keptExcl = woff[w] + lp;
    int slot = keep ? keptExcl : (K + (tid - keptExcl));
    if (slot < MAXDET) {
        float4 bx = boxesWS[b * PRE + tid];
        float cv = clsWS[b * PRE + tid];
        float* o = out + ((size_t)b * MAXDET + slot) * 6;
        o[0] = bx.x; o[1] = bx.y; o[2] = bx.z; o[3] = bx.w;
        o[4] = keep ? sv : 0.0f;
        o[5] = cv;
    }
}

extern "C" void kernel_launch(void* const* d_in, const int* in_sizes, int n_in,
                              void* d_out, int out_size, void* d_ws, size_t ws_size,
                              hipStream_t stream) {
    const float* pred = (const float*)d_in[0];
    float* out = (float*)d_out;
    char* ws = (char*)d_ws;
    float* scores = (float*)(ws + SCORES_OFF);
    unsigned int* gcnt = (unsigned int*)(ws + GCNT_OFF);
    float4* boxesWS = (float4*)(ws + BOXES_OFF);
    float* svalWS = (float*)(ws + SVAL_OFF);
    float* clsWS = (float*)(ws + CLS_OFF);
    unsigned long long* maskC = (unsigned long long*)(ws + MASK_OFF);
    unsigned long long* glist = (unsigned long long*)(ws + GLIST_OFF);

    hipMemsetAsync(ws + GCNT_OFF, 0, GCNT_BYTES, stream);
    k_score<<<dim3((NN + 255) / 256, BB), 256, 0, stream>>>(pred, scores, gcnt, glist);
    k_sort<<<BB, 1024, 0, stream>>>(scores, gcnt, glist, pred,
                                    boxesWS, svalWS, clsWS);
    k_mask<<<dim3(PRE / 4, BB), 256, 0, stream>>>(boxesWS, svalWS, maskC);
    k_nms_out<<<BB, 1024, 0, stream>>>(boxesWS, svalWS, clsWS, maskC, out);
}

// Round 6
// 402.893 us; speedup vs baseline: 1.0388x; 1.0388x over previous
//
#include <hip/hip_runtime.h>
#include <stdint.h>

#define BB 16
#define NN 102000
#define NCLS 35
#define RSTRIDE 40
#define PRE 1024
#define CAP 2048
#define MAXDET 300
#define NBUCK 4096
#define CONF_T 0.25f
#define IOU_T 0.45f
#define BUCK_BASE 0x3E800000u
#define HI_BUCK 3584u        /* bucket of score 0.875; cut lands ~4014 on this data */
#define HI_BITS 0x3F600000u  /* float bits of 0.875 == BUCK_BASE + (HI_BUCK<<12) */
#define GL_CAP 16384         /* per-batch compact-list capacity (~10K expected) */
#define GCNT_STRIDE 64       /* uints between per-batch counters: 256 B apart */

// ---- workspace layout (bytes) ----
#define GCNT_OFF ((size_t)0)
#define GCNT_BYTES ((size_t)BB * GCNT_STRIDE * 4)          // 4,096
#define BOXES_OFF (GCNT_OFF + GCNT_BYTES)
#define BOXES_BYTES ((size_t)BB * PRE * 16)
#define SVAL_OFF (BOXES_OFF + BOXES_BYTES)
#define SVAL_BYTES ((size_t)BB * PRE * 4)
#define CLS_OFF (SVAL_OFF + SVAL_BYTES)
#define CLS_BYTES ((size_t)BB * PRE * 4)
#define MASK_OFF (CLS_OFF + CLS_BYTES)
#define MASK_BYTES ((size_t)BB * PRE * 16 * 8)             // 2 MB
#define GLIST_OFF (MASK_OFF + MASK_BYTES)
#define GLIST_BYTES ((size_t)BB * GL_CAP * 8)              // 2 MB

// padded bitonic index: breaks mod-16 bank aliasing of u64 keys
__device__ __forceinline__ int KS(int i) { return i + (i >> 4); }
#define CAPP (CAP + (CAP >> 4))

// score of one row (exact: fmax tree is exactly assoc/comm, single rounding
// on mc*obj which equals max_j fl(cls_j*obj) by monotonicity, obj>0)
__device__ __forceinline__ float row_score(const float* __restrict__ pred,
                                           int b, int row) {
    const float4* rp = (const float4*)(pred + ((size_t)b * NN + row) * RSTRIDE);
    float4 v1 = rp[1];                     // [obj, cls0, cls1, cls2]
    float4 v2 = rp[2];
    float4 v3 = rp[3];
    float4 v4 = rp[4];
    float4 v5 = rp[5];
    float4 v6 = rp[6];
    float4 v7 = rp[7];
    float4 v8 = rp[8];
    float4 v9 = rp[9];
    float obj = v1.x;
    float m0 = fmaxf(fmaxf(v1.y, v1.z), v1.w);
    float m2 = fmaxf(fmaxf(v2.x, v2.y), fmaxf(v2.z, v2.w));
    float m3 = fmaxf(fmaxf(v3.x, v3.y), fmaxf(v3.z, v3.w));
    float m4 = fmaxf(fmaxf(v4.x, v4.y), fmaxf(v4.z, v4.w));
    float m5 = fmaxf(fmaxf(v5.x, v5.y), fmaxf(v5.z, v5.w));
    float m6 = fmaxf(fmaxf(v6.x, v6.y), fmaxf(v6.z, v6.w));
    float m7 = fmaxf(fmaxf(v7.x, v7.y), fmaxf(v7.z, v7.w));
    float m8 = fmaxf(fmaxf(v8.x, v8.y), fmaxf(v8.z, v8.w));
    float m9 = fmaxf(fmaxf(v9.x, v9.y), fmaxf(v9.z, v9.w));
    float mc = fmaxf(fmaxf(fmaxf(m0, m2), fmaxf(m3, m4)),
                     fmaxf(fmaxf(m5, m6), fmaxf(m7, fmaxf(m8, m9))));
    float conf = mc * obj;
    return (obj > CONF_T && conf > CONF_T) ? conf : 0.0f;
}

// ============================================================
// Kernel 1: per-thread row scoring (R4 structure -- best measured).
// No global histogram, no scores[] write: only the compact >=0.875 list
// is emitted (cut + exact fallback handled in k_sort). Block-aggregated
// returning atomic on a 256B-padded per-batch counter (Round-1 lesson:
// shared-line returning atomics serialized the dispatch to 320us).
// ============================================================
__global__ __launch_bounds__(256) void k_score(const float* __restrict__ pred,
                                               unsigned int* __restrict__ gcnt,
                                               unsigned long long* __restrict__ glist) {
    __shared__ unsigned int sWaveCnt[4];
    __shared__ unsigned int sBase;
    int b = blockIdx.y, tid = threadIdx.x;
    int row = blockIdx.x * 256 + tid;
    float score = 0.0f;
    if (row < NN) score = row_score(pred, b, row);
    unsigned int bits = __float_as_uint(score);
    bool want = (score > 0.0f) && (bits >= HI_BITS);
    unsigned long long m = __ballot(want);
    int lane = tid & 63, w = tid >> 6;
    if (lane == 0) sWaveCnt[w] = (unsigned int)__popcll(m);
    __syncthreads();
    if (tid == 0) {
        unsigned int tot = sWaveCnt[0] + sWaveCnt[1] + sWaveCnt[2] + sWaveCnt[3];
        sBase = tot ? atomicAdd(&gcnt[b * GCNT_STRIDE], tot) : 0u;
    }
    __syncthreads();
    if (want) {
        unsigned int pos = sBase;
        for (int k = 0; k < w; ++k) pos += sWaveCnt[k];
        pos += (unsigned int)__popcll(m & ((1ull << lane) - 1ull));
        if (pos < GL_CAP)
            glist[(size_t)b * GL_CAP + pos] =
                ((unsigned long long)bits << 32) |
                (unsigned int)(~(unsigned int)row);
    }
}

// ============================================================
// Kernel 2 (fused cut+sort): cut from a 512-bucket LDS histogram of the
// compact list. Exact cold path (taken iff <1024 boxes >= 0.875 or list
// overflow -- never on this data): RECOMPUTES scores from pred, builds a
// full 4096-bucket LDS histogram, rescans. Then bitonic sort desc of 2048
// padded keys + top-1024 gather of box/score/cls.
// key = (score_bits << 32) | ~idx  -> u64 desc == (value desc, idx asc)
// ============================================================
__global__ __launch_bounds__(1024) void k_sort(const unsigned int* __restrict__ gcnt,
                                               const unsigned long long* __restrict__ glist,
                                               const float* __restrict__ pred,
                                               float4* __restrict__ boxesWS,
                                               float* __restrict__ svalWS,
                                               float* __restrict__ clsWS) {
    __shared__ int sA[1024], sB[1024];                     // 8 KB
    __shared__ unsigned int hh[512];                       // 2 KB (hot-path hist)
    __shared__ unsigned int fh[NBUCK];                     // 16 KB (cold-path hist)
    __shared__ int cutSh;
    __shared__ unsigned long long keys[CAPP];              // 17.4 KB
    __shared__ unsigned int nloc;
    int b = blockIdx.x, tid = threadIdx.x;
    unsigned int gn = gcnt[b * GCNT_STRIDE];
    if (tid == 0) { cutSh = -1; nloc = 0u; }
    if (tid < 512) hh[tid] = 0u;
    for (int k = tid; k < CAP; k += 1024) keys[KS(k)] = 0ull;
    __syncthreads();
    const unsigned long long* gl = glist + (size_t)b * GL_CAP;
    bool fast = (gn <= (unsigned int)GL_CAP);
    if (fast) {
        for (unsigned int it = tid; it < gn; it += 1024u) {
            unsigned int bits = (unsigned int)(gl[it] >> 32);
            unsigned int bk = (bits - BUCK_BASE) >> 12;
            if (bk > NBUCK - 1u) bk = NBUCK - 1u;
            atomicAdd(&hh[bk - HI_BUCK], 1u);              // bk >= HI_BUCK by constr.
        }
        __syncthreads();
        if (tid < 512) sA[tid] = (int)hh[tid];
        __syncthreads();
        int* src = sA; int* dst = sB;
        for (int off = 1; off < 512; off <<= 1) {
            if (tid < 512) {
                int x = src[tid];
                if (tid + off < 512) x += src[tid + off];
                dst[tid] = x;
            }
            __syncthreads();
            int* t_ = src; src = dst; dst = t_;
        }
        if (tid < 512) {
            int suf = src[tid];
            int nx = (tid + 1 < 512) ? src[tid + 1] : 0;
            if (suf >= PRE && nx < PRE) cutSh = (int)HI_BUCK + tid;
        }
        __syncthreads();
    }
    int cut = cutSh;
    if (fast && cut >= (int)HI_BUCK) {
        // hot gather: compact list fully covers buckets >= cut
        for (unsigned int it = tid; it < gn; it += 1024u) {
            unsigned long long key = gl[it];
            unsigned int bits = (unsigned int)(key >> 32);
            unsigned int bk = (bits - BUCK_BASE) >> 12;
            if (bk > NBUCK - 1u) bk = NBUCK - 1u;
            if ((int)bk >= cut) {
                unsigned int pos = atomicAdd(&nloc, 1u);
                if (pos < CAP) keys[KS((int)pos)] = key;
            }
        }
    } else {
        // cold exact path (never taken on this data): recompute + full hist
        for (int k = tid; k < NBUCK; k += 1024) fh[k] = 0u;
        __syncthreads();
        for (int it = tid; it < NN; it += 1024) {
            float s = row_score(pred, b, it);
            if (s > 0.0f) {
                unsigned int bits = __float_as_uint(s);
                unsigned int bk = (bits - BUCK_BASE) >> 12;
                if (bk > NBUCK - 1u) bk = NBUCK - 1u;
                atomicAdd(&fh[bk], 1u);
            }
        }
        __syncthreads();
        int h0 = fh[4 * tid + 0], h1 = fh[4 * tid + 1];
        int h2 = fh[4 * tid + 2], h3 = fh[4 * tid + 3];
        if (tid == 0) cutSh = 0;
        sA[tid] = h0 + h1 + h2 + h3;
        __syncthreads();
        int* src = sA; int* dst = sB;
        for (int off = 1; off < 1024; off <<= 1) {
            int x = src[tid];
            if (tid + off < 1024) x += src[tid + off];
            dst[tid] = x;
            __syncthreads();
            int* t_ = src; src = dst; dst = t_;
        }
        int nxt = (tid + 1 < 1024) ? src[tid + 1] : 0;
        int s3 = h3 + nxt;
        int s2 = h2 + s3;
        int s1 = h1 + s2;
        int s0 = h0 + s1;
        if (s0 >= PRE && s1 < PRE) cutSh = 4 * tid + 0;
        if (s1 >= PRE && s2 < PRE) cutSh = 4 * tid + 1;
        if (s2 >= PRE && s3 < PRE) cutSh = 4 * tid + 2;
        if (s3 >= PRE && nxt < PRE) cutSh = 4 * tid + 3;
        __syncthreads();
        unsigned int ccut = (unsigned int)cutSh;
        for (int it = tid; it < NN; it += 1024) {
            float s = row_score(pred, b, it);
            if (s > 0.0f) {
                unsigned int bits = __float_as_uint(s);
                unsigned int bk = (bits - BUCK_BASE) >> 12;
                if (bk > NBUCK - 1u) bk = NBUCK - 1u;
                if (bk >= ccut) {
                    unsigned int pos = atomicAdd(&nloc, 1u);
                    if (pos < CAP)
                        keys[KS((int)pos)] = ((unsigned long long)bits << 32) |
                                             (unsigned int)(~(unsigned int)it);
                }
            }
        }
    }
    __syncthreads();

    // ---- bitonic sort desc (padded indices -> no 8-way bank alias) ----
    for (int k = 2; k <= CAP; k <<= 1) {
        for (int j = k >> 1; j > 0; j >>= 1) {
            int p = ((tid & ~(j - 1)) << 1) | (tid & (j - 1));
            int q = p | j;
            int pp = KS(p), qq = KS(q);
            unsigned long long a = keys[pp], c = keys[qq];
            bool desc = (p & k) == 0;
            bool sw = desc ? (a < c) : (a > c);
            if (sw) { keys[pp] = c; keys[qq] = a; }
            __syncthreads();
        }
    }

    // ---- top-1024 gather + box/cls recompute ----
    unsigned long long key = keys[KS(tid)];
    unsigned int bits = (unsigned int)(key >> 32);
    unsigned int idx = ~(unsigned int)key;
    float sc = __uint_as_float(bits);
    if (bits == 0u || idx >= NN) { idx = 0; sc = 0.0f; }   // pad guard
    const float4* row = (const float4*)(pred + ((size_t)b * NN + idx) * RSTRIDE);
    float4 r0 = row[0];
    float4 r1 = row[1];
    float obj = r1.x;
    float best = r1.y * obj; int bj = 0;
    float p1 = r1.z * obj; if (p1 > best) { best = p1; bj = 1; }
    float p2 = r1.w * obj; if (p2 > best) { best = p2; bj = 2; }
#pragma unroll
    for (int kk = 2; kk <= 9; ++kk) {
        float4 r = row[kk];
        int base = (kk - 2) * 4 + 3;
        float q0 = r.x * obj; if (q0 > best) { best = q0; bj = base + 0; }
        float q1 = r.y * obj; if (q1 > best) { best = q1; bj = base + 1; }
        float q2 = r.z * obj; if (q2 > best) { best = q2; bj = base + 2; }
        float q3 = r.w * obj; if (q3 > best) { best = q3; bj = base + 3; }
    }
    float hx = r0.z * 0.5f;   // exact (power-of-two scale)
    float hy = r0.w * 0.5f;
    boxesWS[b * PRE + tid] = make_float4(r0.x - hx, r0.y - hy, r0.x + hx, r0.y + hy);
    svalWS[b * PRE + tid] = sc;
    clsWS[b * PRE + tid] = (float)bj;
}

// ============================================================
// Kernel 3: column-major suppression mask. Wide grid (Round-3 lesson),
// but 1024-thread blocks: 64x16 grid -> 4x fewer LDS stagings of the
// same 24KB box table than the 256x16 version.
// maskC[b][j][c] bit l  <=>  i=64c+l < j  &&  valid[i]  &&  IoU(i,j) > 0.45
// ============================================================
__global__ __launch_bounds__(1024) void k_mask(const float4* __restrict__ boxesWS,
                                               const float* __restrict__ svalWS,
                                               unsigned long long* __restrict__ maskC) {
    __shared__ float bx1[PRE], by1[PRE], bx2[PRE], by2[PRE], bar[PRE], bsv[PRE];
    int b = blockIdx.y, tid = threadIdx.x;
    for (int i = tid; i < PRE; i += 1024) {
        float4 bx = boxesWS[b * PRE + i];
        bx1[i] = bx.x; by1[i] = bx.y; bx2[i] = bx.z; by2[i] = bx.w;
        float aw = fmaxf(bx.z - bx.x, 0.0f);
        float ah = fmaxf(bx.w - bx.y, 0.0f);
        bar[i] = aw * ah;
        bsv[i] = svalWS[b * PRE + i];
    }
    __syncthreads();
    int j = blockIdx.x * 16 + (tid >> 6);
    int lane = tid & 63;
    float jx1 = bx1[j], jy1 = by1[j], jx2 = bx2[j], jy2 = by2[j], ja = bar[j];
    unsigned long long* out = maskC + ((size_t)b * PRE + j) * 16;
    for (int c = 0; c < 16; ++c) {
        unsigned long long word = 0ull;
        if (c * 64 < j) {                      // wave-uniform branch
            int i = c * 64 + lane;
            bool bit = false;
            if (i < j && bsv[i] > 0.0f) {
                float ltx = fmaxf(bx1[i], jx1), lty = fmaxf(by1[i], jy1);
                float rbx = fminf(bx2[i], jx2), rby = fminf(by2[i], jy2);
                float wx = fmaxf(rbx - ltx, 0.0f);
                float wy = fmaxf(rby - lty, 0.0f);
                float inter = wx * wy;                       // two uses -> no contraction
                float denom = ((bar[i] + ja) - inter) + 1e-7f;
                bit = (inter / denom) > IOU_T;               // IEEE divide, like reference
            }
            word = __ballot(bit);
        }
        if (lane == 0) out[c] = word;
    }
}

// ============================================================
// Kernel 4: fixpoint NMS (2 barriers/iter) + exact top-300 ordering.
// ============================================================
__global__ __launch_bounds__(1024) void k_nms_out(const float4* __restrict__ boxesWS,
                                                  const float* __restrict__ svalWS,
                                                  const float* __restrict__ clsWS,
                                                  const unsigned long long* __restrict__ maskC,
                                                  float* __restrict__ out) {
    __shared__ unsigned long long supp[16];
    __shared__ int lastch;
    __shared__ int wtot[16], woff[17];
    int b = blockIdx.x, tid = threadIdx.x;
    int lane = tid & 63, w = tid >> 6;
    unsigned long long cm[16];
    const unsigned long long* mrow = maskC + ((size_t)b * PRE + tid) * 16;
#pragma unroll
    for (int k = 0; k < 16; ++k) cm[k] = mrow[k];
    float sv = svalWS[b * PRE + tid];
    if (tid < 16) supp[tid] = 0ull;
    if (tid == 0) lastch = -1;
    __syncthreads();
    for (int it = 0; it < PRE + 2; ++it) {
        bool nb = false;
#pragma unroll
        for (int k = 0; k < 16; ++k) nb |= ((cm[k] & ~supp[k]) != 0ull);
        unsigned long long word = __ballot(nb);
        __syncthreads();                       // all waves done reading supp
        if (lane == 0) {
            if (word != supp[w]) lastch = it;  // benign same-value multi-writer
            supp[w] = word;
        }
        __syncthreads();                       // supp + lastch published
        if (lastch != it) break;
    }
    bool keep = (sv > 0.0f) && !((supp[w] >> lane) & 1ull);
    unsigned long long km = __ballot(keep);
    int lp = __popcll(km & ((lane == 0) ? 0ull : ((1ull << lane) - 1ull)));
    if (lane == 0) wtot[w] = __popcll(km);
    __syncthreads();
    if (tid == 0) {
        int acc = 0;
        for (int k = 0; k < 16; ++k) { woff[k] = acc; acc += wtot[k]; }
        woff[16] = acc;
    }
    __syncthreads();
    int K = woff[16];
    int keptExcl = woff[w] + lp;
    int slot = keep ? keptExcl : (K + (tid - keptExcl));
    if (slot < MAXDET) {
        float4 bx = boxesWS[b * PRE + tid];
        float cv = clsWS[b * PRE + tid];
        float* o = out + ((size_t)b * MAXDET + slot) * 6;
        o[0] = bx.x; o[1] = bx.y; o[2] = bx.z; o[3] = bx.w;
        o[4] = keep ? sv : 0.0f;
        o[5] = cv;
    }
}

extern "C" void kernel_launch(void* const* d_in, const int* in_sizes, int n_in,
                              void* d_out, int out_size, void* d_ws, size_t ws_size,
                              hipStream_t stream) {
    const float* pred = (const float*)d_in[0];
    float* out = (float*)d_out;
    char* ws = (char*)d_ws;
    unsigned int* gcnt = (unsigned int*)(ws + GCNT_OFF);
    float4* boxesWS = (float4*)(ws + BOXES_OFF);
    float* svalWS = (float*)(ws + SVAL_OFF);
    float* clsWS = (float*)(ws + CLS_OFF);
    unsigned long long* maskC = (unsigned long long*)(ws + MASK_OFF);
    unsigned long long* glist = (unsigned long long*)(ws + GLIST_OFF);

    hipMemsetAsync(ws + GCNT_OFF, 0, GCNT_BYTES, stream);
    k_score<<<dim3((NN + 255) / 256, BB), 256, 0, stream>>>(pred, gcnt, glist);
    k_sort<<<BB, 1024, 0, stream>>>(gcnt, glist, pred, boxesWS, svalWS, clsWS);
    k_mask<<<dim3(PRE / 16, BB), 1024, 0, stream>>>(boxesWS, svalWS, maskC);
    k_nms_out<<<BB, 1024, 0, stream>>>(boxesWS, svalWS, clsWS, maskC, out);
}